// Round 3
// baseline (1579.696 us; speedup 1.0000x reference)
//
#include <hip/hip_runtime.h>

// NSA forward, MI355X round 3: RUNTIME dtype detection (bf16 vs fp32) for
// {q,k,v,out} and {weights} independently; fp32 math everywhere.
// Shapes hardcoded: S=4096, seqlen=2048, qh=8, kvh=2, dim=128,
// D_BLK=L_CMP=L_SLC=BQ=64, TOPK=16, window=(512,0).

#define SEQ   2048
#define NB    2
#define KV    2
#define NH    4
#define QH    8
#define DIM   128
#define NBLK  32
#define NQB   32
#define NTOP  16
#define SCALE 0.08838834764831845f   // 128^-0.5

typedef unsigned short ushort_t;

__device__ __forceinline__ ushort_t f2b(float f){
  union { float f; unsigned i; } x; x.f = f;
  unsigned r = x.i + 0x7fffu + ((x.i >> 16) & 1u);   // RNE
  return (ushort_t)(r >> 16);
}
__device__ __forceinline__ float b2f(ushort_t u){
  union { unsigned i; float f; } x; x.i = ((unsigned)u) << 16; return x.f;
}
__device__ __forceinline__ float ulo(unsigned u){ union{unsigned i; float f;}x; x.i = u<<16;           return x.f; }
__device__ __forceinline__ float uhi(unsigned u){ union{unsigned i; float f;}x; x.i = u & 0xffff0000u; return x.f; }

// generic scalar load: element i of tensor p under dtype flag
__device__ __forceinline__ float ld(const void* p, size_t i, int isbf){
  return isbf ? b2f(((const ushort_t*)p)[i]) : ((const float*)p)[i];
}

// ---------------- kernel 0: dtype detection --------------------------------
// For fp32 data, even-index ushorts are mantissa bits -> wild bf16 exponents.
// For bf16 data, every ushort decodes to a sane value.
__global__ void detect_k(const void* q, const void* wg, int* flags){
  if (threadIdx.x == 0){
    const ushort_t* a = (const ushort_t*)q;
    int sane = 0;
    for (int i = 0; i < 128; ++i){
      float f = b2f(a[2*i]); float m = fabsf(f);
      if (f == f && m > 1e-10f && m < 1e10f) sane++;
    }
    flags[0] = (sane >= 120) ? 1 : 0;
    const ushort_t* b = (const ushort_t*)wg;   // w_gate: >=384 elems either way
    sane = 0;
    for (int i = 0; i < 128; ++i){
      float f = b2f(b[2*i]); float m = fabsf(f);
      if (f == f && m > 1e-10f && m < 1e10f) sane++;
    }
    flags[1] = (sane >= 120) ? 1 : 0;
  }
}

// ---------------- kernel 1: block compression ------------------------------
__global__ __launch_bounds__(256) void compress_k(
    const void* __restrict__ k, const void* __restrict__ v,
    const void* __restrict__ w_k, const void* __restrict__ b_k,
    const void* __restrict__ w_v, const void* __restrict__ b_v,
    const int* __restrict__ flg,
    float* __restrict__ Kc, float* __restrict__ Vc)
{
  int QB = flg[0], WB = flg[1];
  __shared__ float wk[64], wv[64];
  if (threadIdx.x < 64){
    wk[threadIdx.x] = ld(w_k, threadIdx.x, WB);
    wv[threadIdx.x] = ld(w_v, threadIdx.x, WB);
  }
  __syncthreads();
  int t = blockIdx.x * 256 + threadIdx.x;           // over NB*KV*NBLK*DIM = 16384
  if (t >= NB*KV*NBLK*DIM) return;
  int e  = t & (DIM-1);
  int n  = (t >> 7)  & (NBLK-1);
  int g  = (t >> 12) & (KV-1);
  int bb = t >> 13;
  float ak = 0.f, av = 0.f;
  size_t base = ((size_t)(bb*SEQ + n*64) * KV + g) * DIM + e;
  for (int tt = 0; tt < 64; ++tt){
    ak += ld(k, base + (size_t)tt * KV * DIM, QB) * wk[tt];
    av += ld(v, base + (size_t)tt * KV * DIM, QB) * wv[tt];
  }
  Kc[t] = ak + ld(b_k, 0, WB);
  Vc[t] = av + ld(b_v, 0, WB);
}

// q fragment load (32 floats = quarter c of one head row), dtype-branched
__device__ __forceinline__ void load_q32(const void* q, size_t elem_off, int QB, float* qv){
  if (QB){
    const uint4* q4 = (const uint4*)((const ushort_t*)q + elem_off);
#pragma unroll
    for (int j = 0; j < 4; ++j){
      uint4 u = q4[j];
      qv[8*j+0]=ulo(u.x); qv[8*j+1]=uhi(u.x); qv[8*j+2]=ulo(u.y); qv[8*j+3]=uhi(u.y);
      qv[8*j+4]=ulo(u.z); qv[8*j+5]=uhi(u.z); qv[8*j+6]=ulo(u.w); qv[8*j+7]=uhi(u.w);
    }
  } else {
    const float4* q4 = (const float4*)((const float*)q + elem_off);
#pragma unroll
    for (int j = 0; j < 8; ++j){
      float4 u = q4[j];
      qv[4*j+0]=u.x; qv[4*j+1]=u.y; qv[4*j+2]=u.z; qv[4*j+3]=u.w;
    }
  }
}

// stage 32 K/V rows (128 elems each) into fp32 LDS, dtype-branched
__device__ __forceinline__ void stage32(const void* k, const void* v,
                                        float (*Kb)[DIM], float (*Vb)[DIM],
                                        int row0, int g, int QB, int tid){
  if (QB){
    const uint4* k4 = (const uint4*)k;
    const uint4* v4 = (const uint4*)v;
    for (int i = tid; i < 32*16; i += 256){
      int key = i >> 4, seg = i & 15;                 // 16 uint4 per 128-bf16 row
      size_t off = ((size_t)(row0 + key)*KV + g)*16 + seg;
      uint4 u = k4[off];
      float4* dst = (float4*)&Kb[key][seg*8];
      dst[0] = make_float4(ulo(u.x), uhi(u.x), ulo(u.y), uhi(u.y));
      dst[1] = make_float4(ulo(u.z), uhi(u.z), ulo(u.w), uhi(u.w));
      u = v4[off];
      dst = (float4*)&Vb[key][seg*8];
      dst[0] = make_float4(ulo(u.x), uhi(u.x), ulo(u.y), uhi(u.y));
      dst[1] = make_float4(ulo(u.z), uhi(u.z), ulo(u.w), uhi(u.w));
    }
  } else {
    const float4* k4 = (const float4*)k;
    const float4* v4 = (const float4*)v;
    for (int i = tid; i < 32*32; i += 256){
      int key = i >> 5, ve = i & 31;                  // 32 float4 per 128-f32 row
      size_t off = ((size_t)(row0 + key)*KV + g)*32 + ve;
      ((float4*)&Kb[key][ve*4])[0] = k4[off];
      ((float4*)&Vb[key][ve*4])[0] = v4[off];
    }
  }
}

// ------- kernel 2: compressed attention + pooled P -------------------------
__global__ __launch_bounds__(256) void cmp_attn_k(
    const void* __restrict__ q, const float* __restrict__ Kc,
    const float* __restrict__ Vc,
    const void* __restrict__ w_gate, const void* __restrict__ b_gate,
    const int* __restrict__ flg,
    float* __restrict__ pooled, void* __restrict__ out)
{
  int QB = flg[0], WB = flg[1];
  int blk = blockIdx.x;
  int qb = blk & (NQB-1);
  int g  = (blk >> 5) & (KV-1);
  int bb = blk >> 6;
  int tid = threadIdx.x;
  int qi = tid >> 2, c = tid & 3;

  __shared__ float Ks[NBLK*DIM];
  __shared__ float Vs[NBLK*DIM];
  __shared__ float wsum[4][NBLK];

  const float* Ksrc = Kc + (size_t)(bb*KV + g) * NBLK * DIM;
  const float* Vsrc = Vc + (size_t)(bb*KV + g) * NBLK * DIM;
  for (int i = tid; i < NBLK*DIM; i += 256){ Ks[i] = Ksrc[i]; Vs[i] = Vsrc[i]; }
  __syncthreads();

  int row = bb*SEQ + qb*64 + qi;
  float p_acc[NBLK];
#pragma unroll
  for (int n = 0; n < NBLK; ++n) p_acc[n] = 0.f;

  for (int h = 0; h < NH; ++h){
    float qv[32];
    load_q32(q, ((size_t)row*QH + g*NH + h)*DIM + c*32, QB, qv);

    float sc[NBLK];
#pragma unroll
    for (int n = 0; n < NBLK; ++n){
      float p = 0.f;
      const float* kr = Ks + n*DIM + c*32;
#pragma unroll
      for (int d = 0; d < 32; ++d) p += qv[d]*kr[d];
      p += __shfl_xor(p, 1); p += __shfl_xor(p, 2);
      sc[n] = p * SCALE;
    }
    float m = sc[0];
#pragma unroll
    for (int n = 1; n < NBLK; ++n) m = fmaxf(m, sc[n]);
    float l = 0.f;
#pragma unroll
    for (int n = 0; n < NBLK; ++n){ sc[n] = expf(sc[n]-m); l += sc[n]; }
    float inv = 1.f/l;

    float o[32];
#pragma unroll
    for (int d = 0; d < 32; ++d) o[d] = 0.f;
#pragma unroll
    for (int n = 0; n < NBLK; ++n){
      float pn = sc[n]*inv;                 // fp32 P for pooling
      p_acc[n] += pn;
      float pb = QB ? b2f(f2b(pn)) : pn;    // P.astype(q.dtype) for PV
      const float* vr = Vs + n*DIM + c*32;
#pragma unroll
      for (int d = 0; d < 32; ++d) o[d] += pb*vr[d];
    }
    float gp = 0.f;
#pragma unroll
    for (int d = 0; d < 32; ++d) gp += qv[d]*ld(w_gate, (size_t)(c*32+d)*3 + 0, WB);
    gp += __shfl_xor(gp, 1); gp += __shfl_xor(gp, 2);
    float g0 = 1.f/(1.f + expf(-(gp + ld(b_gate, 0, WB))));
    size_t ob = ((size_t)row*QH + g*NH + h)*DIM + c*32;
    if (QB){
      ushort_t* op = (ushort_t*)out + ob;
#pragma unroll
      for (int d = 0; d < 32; ++d) op[d] = f2b(g0*o[d]);
    } else {
      float* op = (float*)out + ob;
#pragma unroll
      for (int d = 0; d < 32; ++d) op[d] = g0*o[d];
    }
  }

#pragma unroll
  for (int n = 0; n < NBLK; ++n){
    float t2 = p_acc[n];
    t2 += __shfl_xor(t2, 4); t2 += __shfl_xor(t2, 8);
    t2 += __shfl_xor(t2, 16); t2 += __shfl_xor(t2, 32);
    p_acc[n] = t2;
  }
  if ((tid & 63) == 0){
    int w = tid >> 6;
#pragma unroll
    for (int n = 0; n < NBLK; ++n) wsum[w][n] = p_acc[n];
  }
  __syncthreads();
  if (tid < NBLK)
    pooled[(size_t)blk*NBLK + tid] = (wsum[0][tid]+wsum[1][tid]) + (wsum[2][tid]+wsum[3][tid]);
}

// ---------------- kernel 3: top-k ------------------------------------------
__global__ void topk_k(const float* __restrict__ pooled, int* __restrict__ idx)
{
  int r = threadIdx.x;
  if (r >= NB*KV*NQB) return;
  float vals[NBLK];
  for (int n = 0; n < NBLK; ++n) vals[n] = pooled[(size_t)r*NBLK + n];
  for (int t = 0; t < NTOP; ++t){
    float best = -INFINITY; int bi = 0;
    for (int n = 0; n < NBLK; ++n)
      if (vals[n] > best){ best = vals[n]; bi = n; }
    idx[r*NTOP + t] = bi;
    vals[bi] = -INFINITY;
  }
}

// ---------------- kernel 4: selected-block attention ------------------------
__global__ __launch_bounds__(256) void slc_attn_k(
    const void* __restrict__ q, const void* __restrict__ k,
    const void* __restrict__ v, const int* __restrict__ idx,
    const void* __restrict__ w_gate, const void* __restrict__ b_gate,
    const int* __restrict__ flg, void* __restrict__ out)
{
  int QB = flg[0], WB = flg[1];
  int blk = blockIdx.x;
  int h  = blk & 3;
  int qb = (blk >> 2) & (NQB-1);
  int g  = (blk >> 7) & 1;
  int bb = blk >> 8;
  int tid = threadIdx.x;
  int qi = tid >> 2, c = tid & 3;

  __shared__ float Kb[32][DIM];   // 16 KB
  __shared__ float Vb[32][DIM];   // 16 KB

  int row = bb*SEQ + qb*64 + qi;
  float qv[32];
  load_q32(q, ((size_t)row*QH + g*NH + h)*DIM + c*32, QB, qv);

  float gp = 0.f;
#pragma unroll
  for (int d = 0; d < 32; ++d) gp += qv[d]*ld(w_gate, (size_t)(c*32+d)*3 + 1, WB);
  gp += __shfl_xor(gp, 1); gp += __shfl_xor(gp, 2);
  float g1 = 1.f/(1.f + expf(-(gp + ld(b_gate, 1, WB))));

  const int* myidx = idx + (size_t)((bb*KV+g)*NQB + qb)*NTOP;

  float m = -INFINITY, l = 0.f;
  float o[32];
#pragma unroll
  for (int d = 0; d < 32; ++d) o[d] = 0.f;

  for (int t = 0; t < NTOP; ++t){
    int n = myidx[t];
    for (int half = 0; half < 2; ++half){
      __syncthreads();
      stage32(k, v, Kb, Vb, bb*SEQ + n*64 + half*32, g, QB, tid);
      __syncthreads();
      float s[32];
      float cmax = -INFINITY;
#pragma unroll
      for (int kk = 0; kk < 32; ++kk){
        float p = 0.f;
        const float4* kr = (const float4*)&Kb[kk][c*32];
#pragma unroll
        for (int j = 0; j < 8; ++j){
          float4 u = kr[j];
          p += qv[4*j+0]*u.x + qv[4*j+1]*u.y + qv[4*j+2]*u.z + qv[4*j+3]*u.w;
        }
        p += __shfl_xor(p, 1); p += __shfl_xor(p, 2);
        s[kk] = p * SCALE;
        cmax = fmaxf(cmax, s[kk]);
      }
      float mn = fmaxf(m, cmax);
      float alpha = expf(m - mn);
      l *= alpha;
#pragma unroll
      for (int d = 0; d < 32; ++d) o[d] *= alpha;
#pragma unroll
      for (int kk = 0; kk < 32; ++kk){
        float pe = expf(s[kk] - mn);
        l += pe;
        const float4* vr = (const float4*)&Vb[kk][c*32];
#pragma unroll
        for (int j = 0; j < 8; ++j){
          float4 u = vr[j];
          o[4*j+0] += pe*u.x; o[4*j+1] += pe*u.y;
          o[4*j+2] += pe*u.z; o[4*j+3] += pe*u.w;
        }
      }
      m = mn;
    }
  }
  float inv = 1.f/l;
  size_t ob = ((size_t)row*QH + g*NH + h)*DIM + c*32;
  if (QB){
    ushort_t* op = (ushort_t*)out + ob;
#pragma unroll
    for (int d = 0; d < 32; ++d) op[d] = f2b(b2f(op[d]) + g1*o[d]*inv);
  } else {
    float* op = (float*)out + ob;
#pragma unroll
    for (int d = 0; d < 32; ++d) op[d] += g1*o[d]*inv;
  }
}

// ---------------- kernel 5: sliding-window attention ------------------------
__global__ __launch_bounds__(256) void win_attn_k(
    const void* __restrict__ q, const void* __restrict__ k,
    const void* __restrict__ v,
    const void* __restrict__ w_gate, const void* __restrict__ b_gate,
    const int* __restrict__ flg, void* __restrict__ out)
{
  int QB = flg[0], WB = flg[1];
  int blk = blockIdx.x;
  int h  = blk & 3;
  int qb = (blk >> 2) & (NQB-1);
  int g  = (blk >> 7) & 1;
  int bb = blk >> 8;
  int tid = threadIdx.x;
  int qi = tid >> 2, c = tid & 3;

  __shared__ float Kb[32][DIM];
  __shared__ float Vb[32][DIM];

  int row = bb*SEQ + qb*64 + qi;
  float qv[32];
  load_q32(q, ((size_t)row*QH + g*NH + h)*DIM + c*32, QB, qv);

  float gp = 0.f;
#pragma unroll
  for (int d = 0; d < 32; ++d) gp += qv[d]*ld(w_gate, (size_t)(c*32+d)*3 + 2, WB);
  gp += __shfl_xor(gp, 1); gp += __shfl_xor(gp, 2);
  float g2 = 1.f/(1.f + expf(-(gp + ld(b_gate, 2, WB))));

  float m = -INFINITY, l = 0.f;
  float o[32];
#pragma unroll
  for (int d = 0; d < 32; ++d) o[d] = 0.f;

  int kb0 = (qb >= 8) ? (qb - 8) : 0;
  for (int kb = kb0; kb <= qb; ++kb){
    bool mlow  = (kb == qb - 8);   // valid: key >= qi
    bool mhigh = (kb == qb);       // valid: key <= qi
    for (int half = 0; half < 2; ++half){
      __syncthreads();
      stage32(k, v, Kb, Vb, bb*SEQ + kb*64 + half*32, g, QB, tid);
      __syncthreads();
      float s[32];
      float cmax = -INFINITY;
#pragma unroll
      for (int kk = 0; kk < 32; ++kk){
        int keyb = half*32 + kk;
        float p = 0.f;
        const float4* kr = (const float4*)&Kb[kk][c*32];
#pragma unroll
        for (int j = 0; j < 8; ++j){
          float4 u = kr[j];
          p += qv[4*j+0]*u.x + qv[4*j+1]*u.y + qv[4*j+2]*u.z + qv[4*j+3]*u.w;
        }
        p += __shfl_xor(p, 1); p += __shfl_xor(p, 2);
        bool valid = (!mlow || keyb >= qi) && (!mhigh || keyb <= qi);
        s[kk] = valid ? (p * SCALE) : -INFINITY;
        cmax = fmaxf(cmax, s[kk]);
      }
      float mn = fmaxf(m, cmax);
      if (mn == -INFINITY) continue;   // fully-masked chunk before first valid key
      float alpha = expf(m - mn);
      l *= alpha;
#pragma unroll
      for (int d = 0; d < 32; ++d) o[d] *= alpha;
#pragma unroll
      for (int kk = 0; kk < 32; ++kk){
        float pe = expf(s[kk] - mn);
        l += pe;
        const float4* vr = (const float4*)&Vb[kk][c*32];
#pragma unroll
        for (int j = 0; j < 8; ++j){
          float4 u = vr[j];
          o[4*j+0] += pe*u.x; o[4*j+1] += pe*u.y;
          o[4*j+2] += pe*u.z; o[4*j+3] += pe*u.w;
        }
      }
      m = mn;
    }
  }
  float inv = 1.f/l;
  size_t ob = ((size_t)row*QH + g*NH + h)*DIM + c*32;
  if (QB){
    ushort_t* op = (ushort_t*)out + ob;
#pragma unroll
    for (int d = 0; d < 32; ++d) op[d] = f2b(b2f(op[d]) + g2*o[d]*inv);
  } else {
    float* op = (float*)out + ob;
#pragma unroll
    for (int d = 0; d < 32; ++d) op[d] += g2*o[d]*inv;
  }
}

extern "C" void kernel_launch(void* const* d_in, const int* in_sizes, int n_in,
                              void* d_out, int out_size, void* d_ws, size_t ws_size,
                              hipStream_t stream) {
  const void* q      = d_in[0];
  const void* k      = d_in[1];
  const void* v      = d_in[2];
  const void* w_k    = d_in[3];
  const void* b_k    = d_in[4];
  const void* w_v    = d_in[5];
  const void* b_v    = d_in[6];
  const void* w_gate = d_in[7];
  const void* b_gate = d_in[8];

  float* ws     = (float*)d_ws;
  int*   flags  = (int*)ws;                 // 16 floats reserved
  float* Kc     = ws + 16;                  // 16384 f32
  float* Vc     = ws + 16 + 16384;          // 16384 f32
  float* pooled = ws + 16 + 32768;          // 4096 f32
  int*   idxb   = (int*)(ws + 16 + 36864);  // 2048 i32

  detect_k  <<<1, 64, 0, stream>>>(q, w_gate, flags);
  compress_k<<<64, 256, 0, stream>>>(k, v, w_k, b_k, w_v, b_v, flags, Kc, Vc);
  cmp_attn_k<<<NB*KV*NQB, 256, 0, stream>>>(q, Kc, Vc, w_gate, b_gate, flags, pooled, d_out);
  topk_k    <<<1, 128, 0, stream>>>(pooled, idxb);
  slc_attn_k<<<NB*KV*NQB*NH, 256, 0, stream>>>(q, k, v, idxb, w_gate, b_gate, flags, d_out);
  win_attn_k<<<NB*KV*NQB*NH, 256, 0, stream>>>(q, k, v, w_gate, b_gate, flags, d_out);
}

// Round 5
// 990.574 us; speedup vs baseline: 1.5947x; 1.5947x over previous
//
#include <hip/hip_runtime.h>

// NSA forward, MI355X round 5. Resolved dtype world (rounds 1/2/3/4 matrix):
// ALL inputs fp32, output fp32. fp32 math. Structure: per-head cmp_attn
// blocks (no spill), stride-36 LDS quarter swizzle (no 4-way conflicts).
// Shapes: S=4096, seqlen=2048, qh=8, kvh=2, dim=128, blocks=64, TOPK=16,
// window=(512,0).

#define SEQ   2048
#define NB    2
#define KV    2
#define NH    4
#define QH    8
#define DIM   128
#define NBLK  32
#define NQB   32
#define NTOP  16
#define SCALE 0.08838834764831845f   // 128^-0.5
#define QS    36                     // LDS quarter stride (floats): 36%32=4
#define RS    144                    // LDS row stride = 4*QS (576 B, 16B-aligned)

// load 32 f32 (quarter c of a 128-dim row)
__device__ __forceinline__ void load_q32(const float* q, size_t elem_off, float* qv){
  const float4* q4 = (const float4*)(q + elem_off);
#pragma unroll
  for (int j = 0; j < 8; ++j){
    float4 u = q4[j];
    qv[4*j+0]=u.x; qv[4*j+1]=u.y; qv[4*j+2]=u.z; qv[4*j+3]=u.w;
  }
}

// stage 32 f32 K/V rows (128 elems) into swizzled LDS
__device__ __forceinline__ void stage32_f32(const float* k, const float* v,
                                            float* Kb, float* Vb,
                                            int row0, int g, int tid){
  const float4* k4 = (const float4*)k;
  const float4* v4 = (const float4*)v;
  for (int i = tid; i < 1024; i += 256){
    int key = i >> 5, seg = i & 31;                 // 32 float4 per 128-f32 row
    size_t off = ((size_t)(row0 + key)*KV + g)*32 + seg;
    int dst = key*RS + (seg>>3)*QS + (seg&7)*4;     // swizzled quarter layout
    ((float4*)(Kb+dst))[0] = k4[off];
    ((float4*)(Vb+dst))[0] = v4[off];
  }
}

// ---------------- kernel 1: block compression (fp32 out to ws) --------------
__global__ __launch_bounds__(256) void compress_k(
    const float* __restrict__ k, const float* __restrict__ v,
    const float* __restrict__ w_k, const float* __restrict__ b_k,
    const float* __restrict__ w_v, const float* __restrict__ b_v,
    float* __restrict__ Kc, float* __restrict__ Vc)
{
  __shared__ float wk[64], wv[64];
  if (threadIdx.x < 64){
    wk[threadIdx.x] = w_k[threadIdx.x];
    wv[threadIdx.x] = w_v[threadIdx.x];
  }
  __syncthreads();
  int t = blockIdx.x * 256 + threadIdx.x;           // over NB*KV*NBLK*DIM = 16384
  if (t >= NB*KV*NBLK*DIM) return;
  int e  = t & (DIM-1);
  int n  = (t >> 7)  & (NBLK-1);
  int g  = (t >> 12) & (KV-1);
  int bb = t >> 13;
  float ak = 0.f, av = 0.f;
  size_t base = ((size_t)(bb*SEQ + n*64) * KV + g) * DIM + e;
  for (int tt = 0; tt < 64; ++tt){
    ak += k[base + (size_t)tt * KV * DIM] * wk[tt];
    av += v[base + (size_t)tt * KV * DIM] * wv[tt];
  }
  Kc[t] = ak + b_k[0];
  Vc[t] = av + b_v[0];
}

// ------- kernel 2: compressed attention, one head per block -----------------
// block = ((bb*KV+g)*NQB+qb)*NH + h ; 256 threads = 64 q x 4 dim-quarters.
// Writes g0*out_cmp (overwrites poison) + per-head pooled partial.
__global__ __launch_bounds__(256) void cmp_attn_k(
    const float* __restrict__ q, const float* __restrict__ Kc,
    const float* __restrict__ Vc,
    const float* __restrict__ w_gate, const float* __restrict__ b_gate,
    float* __restrict__ pooled_part, float* __restrict__ out)
{
  int blk = blockIdx.x;
  int h  = blk & 3;
  int qb = (blk >> 2) & (NQB-1);
  int g  = (blk >> 7) & 1;
  int bb = blk >> 8;
  int tid = threadIdx.x;
  int qi = tid >> 2, c = tid & 3;

  __shared__ float Ks[32*RS];     // 18 KB, swizzled
  __shared__ float Vs[32*RS];     // 18 KB
  __shared__ float wsum[4][NBLK];

  const float4* Ksrc = (const float4*)(Kc + (size_t)(bb*KV + g) * NBLK * DIM);
  const float4* Vsrc = (const float4*)(Vc + (size_t)(bb*KV + g) * NBLK * DIM);
  for (int i = tid; i < 1024; i += 256){            // 32 rows x 32 float4
    int row = i >> 5, seg = i & 31;
    int dst = row*RS + (seg>>3)*QS + (seg&7)*4;
    ((float4*)(Ks+dst))[0] = Ksrc[i];
    ((float4*)(Vs+dst))[0] = Vsrc[i];
  }
  __syncthreads();

  int row = bb*SEQ + qb*64 + qi;
  float qv[32];
  load_q32(q, ((size_t)row*QH + g*NH + h)*DIM + c*32, qv);

  // gate column 0
  float gp = 0.f;
#pragma unroll
  for (int d = 0; d < 32; ++d) gp += qv[d]*w_gate[(c*32+d)*3 + 0];
  gp += __shfl_xor(gp, 1); gp += __shfl_xor(gp, 2);
  float g0 = 1.f/(1.f + expf(-(gp + b_gate[0])));

  float sc[NBLK];
#pragma unroll
  for (int n = 0; n < NBLK; ++n){
    float p = 0.f;
    const float4* kr = (const float4*)(Ks + n*RS + c*QS);
#pragma unroll
    for (int j = 0; j < 8; ++j){
      float4 u = kr[j];
      p += qv[4*j+0]*u.x + qv[4*j+1]*u.y + qv[4*j+2]*u.z + qv[4*j+3]*u.w;
    }
    p += __shfl_xor(p, 1); p += __shfl_xor(p, 2);
    sc[n] = p * SCALE;
  }
  float m = sc[0];
#pragma unroll
  for (int n = 1; n < NBLK; ++n) m = fmaxf(m, sc[n]);
  float l = 0.f;
#pragma unroll
  for (int n = 0; n < NBLK; ++n){ sc[n] = expf(sc[n]-m); l += sc[n]; }
  float inv = 1.f/l;
#pragma unroll
  for (int n = 0; n < NBLK; ++n) sc[n] *= inv;      // P fp32 (q.dtype == f32)

  // pooled partial: deterministic reduce over 16 q per wave, then 4 waves
#pragma unroll
  for (int n = 0; n < NBLK; ++n){
    float t2 = sc[n];
    t2 += __shfl_xor(t2, 4); t2 += __shfl_xor(t2, 8);
    t2 += __shfl_xor(t2, 16); t2 += __shfl_xor(t2, 32);
    if ((tid & 63) == 0) wsum[tid>>6][n] = t2;
  }
  __syncthreads();
  if (tid < NBLK)
    pooled_part[(size_t)blk*NBLK + tid] =
        (wsum[0][tid]+wsum[1][tid]) + (wsum[2][tid]+wsum[3][tid]);

  // PV (P stays fp32 — P.astype(q.dtype) is a no-op)
  float o[32];
#pragma unroll
  for (int d = 0; d < 32; ++d) o[d] = 0.f;
#pragma unroll
  for (int n = 0; n < NBLK; ++n){
    float pb = sc[n];
    const float4* vr = (const float4*)(Vs + n*RS + c*QS);
#pragma unroll
    for (int j = 0; j < 8; ++j){
      float4 u = vr[j];
      o[4*j+0] += pb*u.x; o[4*j+1] += pb*u.y;
      o[4*j+2] += pb*u.z; o[4*j+3] += pb*u.w;
    }
  }
  float* op = out + ((size_t)row*QH + g*NH + h)*DIM + c*32;
#pragma unroll
  for (int d = 0; d < 32; ++d) op[d] = g0*o[d];     // overwrite (first branch)
}

// ---------------- kernel 3: top-k (sums 4 head partials; strict >) ----------
__global__ void topk_k(const float* __restrict__ pp, int* __restrict__ idx)
{
  int r = threadIdx.x;                 // 128 rows = (bb,g,qb)
  if (r >= NB*KV*NQB) return;
  float vals[NBLK];
  for (int n = 0; n < NBLK; ++n){
    const float* p0 = pp + (size_t)(r*NH)*NBLK + n;
    vals[n] = (p0[0] + p0[NBLK]) + (p0[2*NBLK] + p0[3*NBLK]);
  }
  for (int t = 0; t < NTOP; ++t){
    float best = -INFINITY; int bi = 0;
    for (int n = 0; n < NBLK; ++n)
      if (vals[n] > best){ best = vals[n]; bi = n; }
    idx[r*NTOP + t] = bi;
    vals[bi] = -INFINITY;
  }
}

// ---------------- kernel 4: selected-block attention (RMW accumulate) -------
__global__ __launch_bounds__(256) void slc_attn_k(
    const float* __restrict__ q, const float* __restrict__ k,
    const float* __restrict__ v, const int* __restrict__ idx,
    const float* __restrict__ w_gate, const float* __restrict__ b_gate,
    float* __restrict__ out)
{
  int blk = blockIdx.x;
  int h  = blk & 3;
  int qb = (blk >> 2) & (NQB-1);
  int g  = (blk >> 7) & 1;
  int bb = blk >> 8;
  int tid = threadIdx.x;
  int qi = tid >> 2, c = tid & 3;

  __shared__ float Kb[32*RS];   // 18 KB, swizzled
  __shared__ float Vb[32*RS];   // 18 KB

  int row = bb*SEQ + qb*64 + qi;
  float qv[32];
  load_q32(q, ((size_t)row*QH + g*NH + h)*DIM + c*32, qv);

  float gp = 0.f;
#pragma unroll
  for (int d = 0; d < 32; ++d) gp += qv[d]*w_gate[(c*32+d)*3 + 1];
  gp += __shfl_xor(gp, 1); gp += __shfl_xor(gp, 2);
  float g1 = 1.f/(1.f + expf(-(gp + b_gate[1])));

  const int* myidx = idx + (size_t)((bb*KV+g)*NQB + qb)*NTOP;

  float m = -INFINITY, l = 0.f;
  float o[32];
#pragma unroll
  for (int d = 0; d < 32; ++d) o[d] = 0.f;

  for (int t = 0; t < NTOP; ++t){
    int n = myidx[t];
    for (int half = 0; half < 2; ++half){
      __syncthreads();
      stage32_f32(k, v, Kb, Vb, bb*SEQ + n*64 + half*32, g, tid);
      __syncthreads();
      float s[32];
      float cmax = -INFINITY;
#pragma unroll
      for (int kk = 0; kk < 32; ++kk){
        float p = 0.f;
        const float4* kr = (const float4*)(Kb + kk*RS + c*QS);
#pragma unroll
        for (int j = 0; j < 8; ++j){
          float4 u = kr[j];
          p += qv[4*j+0]*u.x + qv[4*j+1]*u.y + qv[4*j+2]*u.z + qv[4*j+3]*u.w;
        }
        p += __shfl_xor(p, 1); p += __shfl_xor(p, 2);
        s[kk] = p * SCALE;
        cmax = fmaxf(cmax, s[kk]);
      }
      float mn = fmaxf(m, cmax);
      float alpha = expf(m - mn);
      l *= alpha;
#pragma unroll
      for (int d = 0; d < 32; ++d) o[d] *= alpha;
#pragma unroll
      for (int kk = 0; kk < 32; ++kk){
        float pe = expf(s[kk] - mn);
        l += pe;
        const float4* vr = (const float4*)(Vb + kk*RS + c*QS);
#pragma unroll
        for (int j = 0; j < 8; ++j){
          float4 u = vr[j];
          o[4*j+0] += pe*u.x; o[4*j+1] += pe*u.y;
          o[4*j+2] += pe*u.z; o[4*j+3] += pe*u.w;
        }
      }
      m = mn;
    }
  }
  float inv = 1.f/l;
  float* op = out + ((size_t)row*QH + g*NH + h)*DIM + c*32;
#pragma unroll
  for (int d = 0; d < 32; ++d) op[d] += g1*o[d]*inv;   // accumulate branch 2
}

// ---------------- kernel 5: sliding-window attention (RMW, final) -----------
__global__ __launch_bounds__(256) void win_attn_k(
    const float* __restrict__ q, const float* __restrict__ k,
    const float* __restrict__ v,
    const float* __restrict__ w_gate, const float* __restrict__ b_gate,
    float* __restrict__ out)
{
  int blk = blockIdx.x;
  int h  = blk & 3;
  int qb = (blk >> 2) & (NQB-1);
  int g  = (blk >> 7) & 1;
  int bb = blk >> 8;
  int tid = threadIdx.x;
  int qi = tid >> 2, c = tid & 3;

  __shared__ float Kb[32*RS];
  __shared__ float Vb[32*RS];

  int row = bb*SEQ + qb*64 + qi;
  float qv[32];
  load_q32(q, ((size_t)row*QH + g*NH + h)*DIM + c*32, qv);

  float gp = 0.f;
#pragma unroll
  for (int d = 0; d < 32; ++d) gp += qv[d]*w_gate[(c*32+d)*3 + 2];
  gp += __shfl_xor(gp, 1); gp += __shfl_xor(gp, 2);
  float g2 = 1.f/(1.f + expf(-(gp + b_gate[2])));

  float m = -INFINITY, l = 0.f;
  float o[32];
#pragma unroll
  for (int d = 0; d < 32; ++d) o[d] = 0.f;

  int kb0 = (qb >= 8) ? (qb - 8) : 0;
  for (int kb = kb0; kb <= qb; ++kb){
    bool mlow  = (kb == qb - 8);   // valid: key >= qi
    bool mhigh = (kb == qb);       // valid: key <= qi
    for (int half = 0; half < 2; ++half){
      __syncthreads();
      stage32_f32(k, v, Kb, Vb, bb*SEQ + kb*64 + half*32, g, tid);
      __syncthreads();
      float s[32];
      float cmax = -INFINITY;
#pragma unroll
      for (int kk = 0; kk < 32; ++kk){
        int keyb = half*32 + kk;
        float p = 0.f;
        const float4* kr = (const float4*)(Kb + kk*RS + c*QS);
#pragma unroll
        for (int j = 0; j < 8; ++j){
          float4 u = kr[j];
          p += qv[4*j+0]*u.x + qv[4*j+1]*u.y + qv[4*j+2]*u.z + qv[4*j+3]*u.w;
        }
        p += __shfl_xor(p, 1); p += __shfl_xor(p, 2);
        bool valid = (!mlow || keyb >= qi) && (!mhigh || keyb <= qi);
        s[kk] = valid ? (p * SCALE) : -INFINITY;
        cmax = fmaxf(cmax, s[kk]);
      }
      float mn = fmaxf(m, cmax);
      if (mn == -INFINITY) continue;   // fully-masked chunk before first valid key
      float alpha = expf(m - mn);
      l *= alpha;
#pragma unroll
      for (int d = 0; d < 32; ++d) o[d] *= alpha;
#pragma unroll
      for (int kk = 0; kk < 32; ++kk){
        float pe = expf(s[kk] - mn);
        l += pe;
        const float4* vr = (const float4*)(Vb + kk*RS + c*QS);
#pragma unroll
        for (int j = 0; j < 8; ++j){
          float4 u = vr[j];
          o[4*j+0] += pe*u.x; o[4*j+1] += pe*u.y;
          o[4*j+2] += pe*u.z; o[4*j+3] += pe*u.w;
        }
      }
      m = mn;
    }
  }
  float inv = 1.f/l;
  float* op = out + ((size_t)row*QH + g*NH + h)*DIM + c*32;
#pragma unroll
  for (int d = 0; d < 32; ++d) op[d] += g2*o[d]*inv;   // accumulate branch 3
}

extern "C" void kernel_launch(void* const* d_in, const int* in_sizes, int n_in,
                              void* d_out, int out_size, void* d_ws, size_t ws_size,
                              hipStream_t stream) {
  const float* q      = (const float*)d_in[0];
  const float* k      = (const float*)d_in[1];
  const float* v      = (const float*)d_in[2];
  const float* w_k    = (const float*)d_in[3];
  const float* b_k    = (const float*)d_in[4];
  const float* w_v    = (const float*)d_in[5];
  const float* b_v    = (const float*)d_in[6];
  const float* w_gate = (const float*)d_in[7];
  const float* b_gate = (const float*)d_in[8];
  float* out = (float*)d_out;

  float* ws     = (float*)d_ws;
  float* Kc     = ws;                       // 16384 f32
  float* Vc     = ws + 16384;               // 16384 f32
  float* pp     = ws + 32768;               // 512*32 = 16384 f32 (per-head pooled)
  int*   idxb   = (int*)(ws + 49152);       // 2048 i32

  compress_k<<<64, 256, 0, stream>>>(k, v, w_k, b_k, w_v, b_v, Kc, Vc);
  cmp_attn_k<<<NB*KV*NQB*NH, 256, 0, stream>>>(q, Kc, Vc, w_gate, b_gate, pp, out);
  topk_k    <<<1, 128, 0, stream>>>(pp, idxb);
  slc_attn_k<<<NB*KV*NQB*NH, 256, 0, stream>>>(q, k, v, idxb, w_gate, b_gate, out);
  win_attn_k<<<NB*KV*NQB*NH, 256, 0, stream>>>(q, k, v, w_gate, b_gate, out);
}

// Round 6
// 320.684 us; speedup vs baseline: 4.9260x; 3.0889x over previous
//
#include <hip/hip_runtime.h>

// NSA forward, MI355X round 6. Dtypes: all inputs fp32, output fp32.
// slc/win attention rewritten on MFMA (bf16 in, fp32 acc): round-5 counters
// showed slc at the ds_read_b128 BW ceiling (83 B/cyc/CU); MFMA raises
// FLOP per LDS byte 16x. cmp/compress/topk kept fp32-VALU (exact top-k).
// Shapes: S=4096, seqlen=2048, qh=8, kvh=2, dim=128, blk=64, TOPK=16,
// window=(512,0).

#define SEQ   2048
#define NB    2
#define KV    2
#define NH    4
#define QH    8
#define DIM   128
#define NBLK  32
#define NQB   32
#define NTOP  16
#define SCALE 0.08838834764831845f   // 128^-0.5
#define QS    36                     // cmp LDS quarter stride (floats)
#define RS    144                    // cmp LDS row stride
#define QP    136                    // Q/K LDS row stride (bf16): pad 8
#define VP    72                     // VT/P LDS row stride (bf16): pad 8

typedef unsigned short ushort_t;
using bf16x8 = __attribute__((ext_vector_type(8))) short;
using f32x4  = __attribute__((ext_vector_type(4))) float;

__device__ __forceinline__ ushort_t f2b(float f){
  union { float f; unsigned i; } x; x.f = f;
  unsigned r = x.i + 0x7fffu + ((x.i >> 16) & 1u);   // RNE
  return (ushort_t)(r >> 16);
}
__device__ __forceinline__ float b2f(ushort_t u){
  union { unsigned i; float f; } x; x.i = ((unsigned)u) << 16; return x.f;
}

// stage 64 rows x 128 f32 (row stride rstride floats) -> bf16 LDS, stride QP
__device__ __forceinline__ void stage_rows_bf16(const float* __restrict__ base,
                                                int rstride, short* dst, int tid){
  for (int i = tid; i < 2048; i += 256){
    int r = i >> 5, s4 = i & 31;
    float4 u = ((const float4*)(base + (size_t)r*rstride))[s4];
    short4 pk;
    pk.x = (short)f2b(u.x); pk.y = (short)f2b(u.y);
    pk.z = (short)f2b(u.z); pk.w = (short)f2b(u.w);
    *(short4*)&dst[r*QP + s4*4] = pk;
  }
}

// stage 64 keys x 128 f32 -> TRANSPOSED bf16 LDS: dst[dim*VP + key]
__device__ __forceinline__ void stage_vt_bf16(const float* __restrict__ base,
                                              int rstride, short* dst, int tid){
  for (int i = tid; i < 2048; i += 256){
    int key = i & 63, f4 = i >> 6;
    float4 u = ((const float4*)(base + (size_t)key*rstride))[f4];
    dst[(f4*4+0)*VP + key] = (short)f2b(u.x);
    dst[(f4*4+1)*VP + key] = (short)f2b(u.y);
    dst[(f4*4+2)*VP + key] = (short)f2b(u.z);
    dst[(f4*4+3)*VP + key] = (short)f2b(u.w);
  }
}

// ---------------- kernel 1: block compression (fp32 out to ws) --------------
__global__ __launch_bounds__(256) void compress_k(
    const float* __restrict__ k, const float* __restrict__ v,
    const float* __restrict__ w_k, const float* __restrict__ b_k,
    const float* __restrict__ w_v, const float* __restrict__ b_v,
    float* __restrict__ Kc, float* __restrict__ Vc)
{
  __shared__ float wk[64], wv[64];
  if (threadIdx.x < 64){
    wk[threadIdx.x] = w_k[threadIdx.x];
    wv[threadIdx.x] = w_v[threadIdx.x];
  }
  __syncthreads();
  int t = blockIdx.x * 256 + threadIdx.x;
  if (t >= NB*KV*NBLK*DIM) return;
  int e  = t & (DIM-1);
  int n  = (t >> 7)  & (NBLK-1);
  int g  = (t >> 12) & (KV-1);
  int bb = t >> 13;
  float ak = 0.f, av = 0.f;
  size_t base = ((size_t)(bb*SEQ + n*64) * KV + g) * DIM + e;
  for (int tt = 0; tt < 64; ++tt){
    ak += k[base + (size_t)tt * KV * DIM] * wk[tt];
    av += v[base + (size_t)tt * KV * DIM] * wv[tt];
  }
  Kc[t] = ak + b_k[0];
  Vc[t] = av + b_v[0];
}

// ------- kernel 2: compressed attention (fp32 VALU; exact pooled P) ---------
__global__ __launch_bounds__(256) void cmp_attn_k(
    const float* __restrict__ q, const float* __restrict__ Kc,
    const float* __restrict__ Vc,
    const float* __restrict__ w_gate, const float* __restrict__ b_gate,
    float* __restrict__ pooled_part, float* __restrict__ out)
{
  int blk = blockIdx.x;
  int h  = blk & 3;
  int qb = (blk >> 2) & (NQB-1);
  int g  = (blk >> 7) & 1;
  int bb = blk >> 8;
  int tid = threadIdx.x;
  int qi = tid >> 2, c = tid & 3;

  __shared__ float Ks[32*RS];
  __shared__ float Vs[32*RS];
  __shared__ float wsum[4][NBLK];

  const float4* Ksrc = (const float4*)(Kc + (size_t)(bb*KV + g) * NBLK * DIM);
  const float4* Vsrc = (const float4*)(Vc + (size_t)(bb*KV + g) * NBLK * DIM);
  for (int i = tid; i < 1024; i += 256){
    int row = i >> 5, seg = i & 31;
    int dst = row*RS + (seg>>3)*QS + (seg&7)*4;
    ((float4*)(Ks+dst))[0] = Ksrc[i];
    ((float4*)(Vs+dst))[0] = Vsrc[i];
  }
  __syncthreads();

  int row = bb*SEQ + qb*64 + qi;
  float qv[32];
  {
    const float4* q4 = (const float4*)(q + ((size_t)row*QH + g*NH + h)*DIM + c*32);
#pragma unroll
    for (int j = 0; j < 8; ++j){
      float4 u = q4[j];
      qv[4*j+0]=u.x; qv[4*j+1]=u.y; qv[4*j+2]=u.z; qv[4*j+3]=u.w;
    }
  }

  float gp = 0.f;
#pragma unroll
  for (int d = 0; d < 32; ++d) gp += qv[d]*w_gate[(c*32+d)*3 + 0];
  gp += __shfl_xor(gp, 1); gp += __shfl_xor(gp, 2);
  float g0 = 1.f/(1.f + expf(-(gp + b_gate[0])));

  float sc[NBLK];
#pragma unroll
  for (int n = 0; n < NBLK; ++n){
    float p = 0.f;
    const float4* kr = (const float4*)(Ks + n*RS + c*QS);
#pragma unroll
    for (int j = 0; j < 8; ++j){
      float4 u = kr[j];
      p += qv[4*j+0]*u.x + qv[4*j+1]*u.y + qv[4*j+2]*u.z + qv[4*j+3]*u.w;
    }
    p += __shfl_xor(p, 1); p += __shfl_xor(p, 2);
    sc[n] = p * SCALE;
  }
  float m = sc[0];
#pragma unroll
  for (int n = 1; n < NBLK; ++n) m = fmaxf(m, sc[n]);
  float l = 0.f;
#pragma unroll
  for (int n = 0; n < NBLK; ++n){ sc[n] = expf(sc[n]-m); l += sc[n]; }
  float inv = 1.f/l;
#pragma unroll
  for (int n = 0; n < NBLK; ++n) sc[n] *= inv;

#pragma unroll
  for (int n = 0; n < NBLK; ++n){
    float t2 = sc[n];
    t2 += __shfl_xor(t2, 4); t2 += __shfl_xor(t2, 8);
    t2 += __shfl_xor(t2, 16); t2 += __shfl_xor(t2, 32);
    if ((tid & 63) == 0) wsum[tid>>6][n] = t2;
  }
  __syncthreads();
  if (tid < NBLK)
    pooled_part[(size_t)blk*NBLK + tid] =
        (wsum[0][tid]+wsum[1][tid]) + (wsum[2][tid]+wsum[3][tid]);

  float o[32];
#pragma unroll
  for (int d = 0; d < 32; ++d) o[d] = 0.f;
#pragma unroll
  for (int n = 0; n < NBLK; ++n){
    float pb = sc[n];
    const float4* vr = (const float4*)(Vs + n*RS + c*QS);
#pragma unroll
    for (int j = 0; j < 8; ++j){
      float4 u = vr[j];
      o[4*j+0] += pb*u.x; o[4*j+1] += pb*u.y;
      o[4*j+2] += pb*u.z; o[4*j+3] += pb*u.w;
    }
  }
  float* op = out + ((size_t)row*QH + g*NH + h)*DIM + c*32;
#pragma unroll
  for (int d = 0; d < 32; ++d) op[d] = g0*o[d];
}

// ---------------- kernel 3: top-k ------------------------------------------
__global__ void topk_k(const float* __restrict__ pp, int* __restrict__ idx)
{
  int r = threadIdx.x;
  if (r >= NB*KV*NQB) return;
  float vals[NBLK];
  for (int n = 0; n < NBLK; ++n){
    const float* p0 = pp + (size_t)(r*NH)*NBLK + n;
    vals[n] = (p0[0] + p0[NBLK]) + (p0[2*NBLK] + p0[3*NBLK]);
  }
  for (int t = 0; t < NTOP; ++t){
    float best = -INFINITY; int bi = 0;
    for (int n = 0; n < NBLK; ++n)
      if (vals[n] > best){ best = vals[n]; bi = n; }
    idx[r*NTOP + t] = bi;
    vals[bi] = -INFINITY;
  }
}

// ---------------- kernel 4: selected-block attention (MFMA) -----------------
// block=(bb,g,qb,h); 4 waves x 16-q strips. Layouts (m89/m91/m120-verified):
// A[m=lane&15][k=quad*8+j], B[k=quad*8+j][n=lane&15], C[col=lane&15,row=quad*4+r]
__global__ __launch_bounds__(256) void slc_attn_k(
    const float* __restrict__ q, const float* __restrict__ k,
    const float* __restrict__ v, const int* __restrict__ idx,
    const float* __restrict__ w_gate, const float* __restrict__ b_gate,
    float* __restrict__ out)
{
  int blk = blockIdx.x;
  int h  = blk & 3;
  int qb = (blk >> 2) & (NQB-1);
  int g  = (blk >> 7) & 1;
  int bb = blk >> 8;
  int tid = threadIdx.x;
  int lane = tid & 63, w = tid >> 6, quad = lane >> 4, l15 = lane & 15;

  __shared__ short Qs[64*QP];    // 17.4 KB
  __shared__ short Ks[64*QP];    // 17.4 KB
  __shared__ short VTs[128*VP];  // 18.4 KB (transposed V)
  __shared__ short Ps[64*VP];    //  9.2 KB
  __shared__ float gbuf[64];

  const float* qbase = q + ((size_t)(bb*SEQ + qb*64)*QH + g*NH + h)*DIM;
  stage_rows_bf16(qbase, QH*DIM, Qs, tid);
  __syncthreads();

  {  // gate col 1 (from bf16 Q; error ~1e-3, within budget)
    int grow = tid >> 2, gc = tid & 3;
    float gp = 0.f;
    for (int jj = 0; jj < 32; ++jj)
      gp += b2f((ushort_t)Qs[grow*QP + gc*32 + jj]) * w_gate[(gc*32+jj)*3 + 1];
    gp += __shfl_xor(gp, 1); gp += __shfl_xor(gp, 2);
    if (gc == 0) gbuf[grow] = 1.f/(1.f + __expf(-(gp + b_gate[1])));
  }

  bf16x8 qfrag[4];
#pragma unroll
  for (int kc = 0; kc < 4; ++kc)
    qfrag[kc] = *(bf16x8*)&Qs[(w*16 + l15)*QP + kc*32 + quad*8];

  __syncthreads();
  float gl[4];
#pragma unroll
  for (int r = 0; r < 4; ++r) gl[r] = gbuf[w*16 + quad*4 + r];

  const int* myidx = idx + ((bb*KV+g)*NQB + qb)*NTOP;

  float m2[4], l2[4];
  f32x4 oacc[8];
  const f32x4 zero4 = {0.f,0.f,0.f,0.f};
#pragma unroll
  for (int r = 0; r < 4; ++r){ m2[r] = -INFINITY; l2[r] = 0.f; }
#pragma unroll
  for (int dt = 0; dt < 8; ++dt) oacc[dt] = zero4;

  for (int t = 0; t < NTOP; ++t){
    int n = myidx[t];
    __syncthreads();
    const float* kb_ = k + ((size_t)(bb*SEQ + n*64)*KV + g)*DIM;
    const float* vb_ = v + ((size_t)(bb*SEQ + n*64)*KV + g)*DIM;
    stage_rows_bf16(kb_, KV*DIM, Ks, tid);
    stage_vt_bf16 (vb_, KV*DIM, VTs, tid);
    __syncthreads();

    f32x4 sacc[4];
#pragma unroll
    for (int nt = 0; nt < 4; ++nt) sacc[nt] = zero4;
#pragma unroll
    for (int kc = 0; kc < 4; ++kc){
      bf16x8 a = qfrag[kc];
#pragma unroll
      for (int nt = 0; nt < 4; ++nt){
        bf16x8 b = *(bf16x8*)&Ks[(nt*16 + l15)*QP + kc*32 + quad*8];
        sacc[nt] = __builtin_amdgcn_mfma_f32_16x16x32_bf16(a, b, sacc[nt], 0, 0, 0);
      }
    }

    float alpha[4];
#pragma unroll
    for (int r = 0; r < 4; ++r){
      float mx = -INFINITY;
#pragma unroll
      for (int nt = 0; nt < 4; ++nt){
        float sv = sacc[nt][r]*SCALE;
        sacc[nt][r] = sv;
        mx = fmaxf(mx, sv);
      }
      mx = fmaxf(mx, __shfl_xor(mx,1)); mx = fmaxf(mx, __shfl_xor(mx,2));
      mx = fmaxf(mx, __shfl_xor(mx,4)); mx = fmaxf(mx, __shfl_xor(mx,8));
      float mn = fmaxf(m2[r], mx);
      alpha[r] = __expf(m2[r] - mn);
      float s0 = 0.f;
#pragma unroll
      for (int nt = 0; nt < 4; ++nt){
        float pe = __expf(sacc[nt][r] - mn);
        sacc[nt][r] = pe;
        s0 += pe;
      }
      s0 += __shfl_xor(s0,1); s0 += __shfl_xor(s0,2);
      s0 += __shfl_xor(s0,4); s0 += __shfl_xor(s0,8);
      l2[r] = l2[r]*alpha[r] + s0;
      m2[r] = mn;
    }

    // P: C-layout -> LDS row-major (A-layout source); same-wave round-trip
#pragma unroll
    for (int nt = 0; nt < 4; ++nt)
#pragma unroll
      for (int r = 0; r < 4; ++r)
        Ps[(w*16 + quad*4 + r)*VP + nt*16 + l15] = (short)f2b(sacc[nt][r]);

#pragma unroll
    for (int dt = 0; dt < 8; ++dt)
#pragma unroll
      for (int r = 0; r < 4; ++r) oacc[dt][r] *= alpha[r];

#pragma unroll
    for (int kc2 = 0; kc2 < 2; ++kc2){
      bf16x8 pa = *(bf16x8*)&Ps[(w*16 + l15)*VP + kc2*32 + quad*8];
#pragma unroll
      for (int dt = 0; dt < 8; ++dt){
        bf16x8 vb8 = *(bf16x8*)&VTs[(dt*16 + l15)*VP + kc2*32 + quad*8];
        oacc[dt] = __builtin_amdgcn_mfma_f32_16x16x32_bf16(pa, vb8, oacc[dt], 0, 0, 0);
      }
    }
  }

#pragma unroll
  for (int r = 0; r < 4; ++r){
    int qrow = qb*64 + w*16 + quad*4 + r;
    float sc2 = gl[r] / l2[r];
    float* op = out + ((size_t)(bb*SEQ + qrow)*QH + g*NH + h)*DIM + l15;
#pragma unroll
    for (int dt = 0; dt < 8; ++dt)
      op[dt*16] += sc2 * oacc[dt][r];      // accumulate branch 2
  }
}

// ---------------- kernel 5: sliding-window attention (MFMA, final) ----------
__global__ __launch_bounds__(256) void win_attn_k(
    const float* __restrict__ q, const float* __restrict__ k,
    const float* __restrict__ v,
    const float* __restrict__ w_gate, const float* __restrict__ b_gate,
    float* __restrict__ out)
{
  int blk = blockIdx.x;
  int h  = blk & 3;
  int qb = (blk >> 2) & (NQB-1);
  int g  = (blk >> 7) & 1;
  int bb = blk >> 8;
  int tid = threadIdx.x;
  int lane = tid & 63, w = tid >> 6, quad = lane >> 4, l15 = lane & 15;

  __shared__ short Qs[64*QP];
  __shared__ short Ks[64*QP];
  __shared__ short VTs[128*VP];
  __shared__ short Ps[64*VP];
  __shared__ float gbuf[64];

  const float* qbase = q + ((size_t)(bb*SEQ + qb*64)*QH + g*NH + h)*DIM;
  stage_rows_bf16(qbase, QH*DIM, Qs, tid);
  __syncthreads();

  {  // gate col 2
    int grow = tid >> 2, gc = tid & 3;
    float gp = 0.f;
    for (int jj = 0; jj < 32; ++jj)
      gp += b2f((ushort_t)Qs[grow*QP + gc*32 + jj]) * w_gate[(gc*32+jj)*3 + 2];
    gp += __shfl_xor(gp, 1); gp += __shfl_xor(gp, 2);
    if (gc == 0) gbuf[grow] = 1.f/(1.f + __expf(-(gp + b_gate[2])));
  }

  bf16x8 qfrag[4];
#pragma unroll
  for (int kc = 0; kc < 4; ++kc)
    qfrag[kc] = *(bf16x8*)&Qs[(w*16 + l15)*QP + kc*32 + quad*8];

  __syncthreads();
  float gl[4];
#pragma unroll
  for (int r = 0; r < 4; ++r) gl[r] = gbuf[w*16 + quad*4 + r];

  float m2[4], l2[4];
  f32x4 oacc[8];
  const f32x4 zero4 = {0.f,0.f,0.f,0.f};
#pragma unroll
  for (int r = 0; r < 4; ++r){ m2[r] = -INFINITY; l2[r] = 0.f; }
#pragma unroll
  for (int dt = 0; dt < 8; ++dt) oacc[dt] = zero4;

  int kb0 = (qb >= 8) ? (qb - 8) : 0;
  for (int kb = kb0; kb <= qb; ++kb){
    bool mlow  = (kb == qb - 8);   // valid: key >= qi
    bool mhigh = (kb == qb);       // valid: key <= qi
    __syncthreads();
    const float* kb_ = k + ((size_t)(bb*SEQ + kb*64)*KV + g)*DIM;
    const float* vb_ = v + ((size_t)(bb*SEQ + kb*64)*KV + g)*DIM;
    stage_rows_bf16(kb_, KV*DIM, Ks, tid);
    stage_vt_bf16 (vb_, KV*DIM, VTs, tid);
    __syncthreads();

    f32x4 sacc[4];
#pragma unroll
    for (int nt = 0; nt < 4; ++nt) sacc[nt] = zero4;
#pragma unroll
    for (int kc = 0; kc < 4; ++kc){
      bf16x8 a = qfrag[kc];
#pragma unroll
      for (int nt = 0; nt < 4; ++nt){
        bf16x8 b = *(bf16x8*)&Ks[(nt*16 + l15)*QP + kc*32 + quad*8];
        sacc[nt] = __builtin_amdgcn_mfma_f32_16x16x32_bf16(a, b, sacc[nt], 0, 0, 0);
      }
    }

    float alpha[4];
#pragma unroll
    for (int r = 0; r < 4; ++r){
      int qi_local = w*16 + quad*4 + r;
      float mx = -INFINITY;
#pragma unroll
      for (int nt = 0; nt < 4; ++nt){
        int key = nt*16 + l15;
        float sv = sacc[nt][r]*SCALE;
        bool valid = (!mlow || key >= qi_local) && (!mhigh || key <= qi_local);
        sv = valid ? sv : -INFINITY;
        sacc[nt][r] = sv;
        mx = fmaxf(mx, sv);
      }
      mx = fmaxf(mx, __shfl_xor(mx,1)); mx = fmaxf(mx, __shfl_xor(mx,2));
      mx = fmaxf(mx, __shfl_xor(mx,4)); mx = fmaxf(mx, __shfl_xor(mx,8));
      float mn = fmaxf(m2[r], mx);
      alpha[r] = __expf(m2[r] - mn);
      float s0 = 0.f;
#pragma unroll
      for (int nt = 0; nt < 4; ++nt){
        float pe = __expf(sacc[nt][r] - mn);   // exp(-inf - mn) = 0 for masked
        sacc[nt][r] = pe;
        s0 += pe;
      }
      s0 += __shfl_xor(s0,1); s0 += __shfl_xor(s0,2);
      s0 += __shfl_xor(s0,4); s0 += __shfl_xor(s0,8);
      l2[r] = l2[r]*alpha[r] + s0;
      m2[r] = mn;
    }

#pragma unroll
    for (int nt = 0; nt < 4; ++nt)
#pragma unroll
      for (int r = 0; r < 4; ++r)
        Ps[(w*16 + quad*4 + r)*VP + nt*16 + l15] = (short)f2b(sacc[nt][r]);

#pragma unroll
    for (int dt = 0; dt < 8; ++dt)
#pragma unroll
      for (int r = 0; r < 4; ++r) oacc[dt][r] *= alpha[r];

#pragma unroll
    for (int kc2 = 0; kc2 < 2; ++kc2){
      bf16x8 pa = *(bf16x8*)&Ps[(w*16 + l15)*VP + kc2*32 + quad*8];
#pragma unroll
      for (int dt = 0; dt < 8; ++dt){
        bf16x8 vb8 = *(bf16x8*)&VTs[(dt*16 + l15)*VP + kc2*32 + quad*8];
        oacc[dt] = __builtin_amdgcn_mfma_f32_16x16x32_bf16(pa, vb8, oacc[dt], 0, 0, 0);
      }
    }
  }

#pragma unroll
  for (int r = 0; r < 4; ++r){
    int qrow = qb*64 + w*16 + quad*4 + r;
    float sc2 = gl[r] / l2[r];
    float* op = out + ((size_t)(bb*SEQ + qrow)*QH + g*NH + h)*DIM + l15;
#pragma unroll
    for (int dt = 0; dt < 8; ++dt)
      op[dt*16] += sc2 * oacc[dt][r];      // accumulate branch 3
  }
}

extern "C" void kernel_launch(void* const* d_in, const int* in_sizes, int n_in,
                              void* d_out, int out_size, void* d_ws, size_t ws_size,
                              hipStream_t stream) {
  const float* q      = (const float*)d_in[0];
  const float* k      = (const float*)d_in[1];
  const float* v      = (const float*)d_in[2];
  const float* w_k    = (const float*)d_in[3];
  const float* b_k    = (const float*)d_in[4];
  const float* w_v    = (const float*)d_in[5];
  const float* b_v    = (const float*)d_in[6];
  const float* w_gate = (const float*)d_in[7];
  const float* b_gate = (const float*)d_in[8];
  float* out = (float*)d_out;

  float* ws     = (float*)d_ws;
  float* Kc     = ws;                       // 16384 f32
  float* Vc     = ws + 16384;               // 16384 f32
  float* pp     = ws + 32768;               // 512*32 f32
  int*   idxb   = (int*)(ws + 49152);       // 2048 i32

  compress_k<<<64, 256, 0, stream>>>(k, v, w_k, b_k, w_v, b_v, Kc, Vc);
  cmp_attn_k<<<NB*KV*NQB*NH, 256, 0, stream>>>(q, Kc, Vc, w_gate, b_gate, pp, out);
  topk_k    <<<1, 128, 0, stream>>>(pp, idxb);
  slc_attn_k<<<NB*KV*NQB*NH, 256, 0, stream>>>(q, k, v, idxb, w_gate, b_gate, out);
  win_attn_k<<<NB*KV*NQB*NH, 256, 0, stream>>>(q, k, v, w_gate, b_gate, out);
}

// Round 7
// 304.169 us; speedup vs baseline: 5.1935x; 1.0543x over previous
//
#include <hip/hip_runtime.h>
#include <hip/hip_bf16.h>

// NSA forward, MI355X round 7. All inputs fp32, output fp32.
// attn_k = fused topk + selected + window attention (MFMA bf16, fp32 acc):
// direct global->reg Q fragments (no Q LDS; 44.6 KB -> 3 blocks/CU),
// v_cvt_pk_bf16_f32 staging, per-block shuffle-butterfly topk.
// cmp kept fp32-VALU so pooled scores / top-k match the reference exactly.
// Shapes: S=4096, seqlen=2048, qh=8, kvh=2, dim=128, blk=64, TOPK=16,
// window=(512,0).

#define SEQ   2048
#define NB    2
#define KV    2
#define NH    4
#define QH    8
#define DIM   128
#define NBLK  32
#define NQB   32
#define NTOP  16
#define SCALE 0.08838834764831845f   // 128^-0.5
#define QS    36                     // cmp LDS quarter stride (floats)
#define RS    144                    // cmp LDS row stride
#define QP    136                    // K LDS row stride (bf16): pad 8
#define VP    72                     // VT/P LDS row stride (bf16): pad 8

typedef unsigned short ushort_t;
using bf16x8 = __attribute__((ext_vector_type(8))) short;
using f32x4  = __attribute__((ext_vector_type(4))) float;

__device__ __forceinline__ unsigned pkbf(float a, float b){
  union { __hip_bfloat162 h; unsigned u; } cv;
  cv.h = __float22bfloat162_rn(make_float2(a, b));
  return cv.u;
}
__device__ __forceinline__ ushort_t f2b(float f){
  union { float f; unsigned i; } x; x.f = f;
  unsigned r = x.i + 0x7fffu + ((x.i >> 16) & 1u);   // RNE
  return (ushort_t)(r >> 16);
}

// 64 keys x 128 f32 (stride KV*DIM) -> bf16 LDS rows, stride QP
__device__ __forceinline__ void stage_k_bf16(const float* __restrict__ base,
                                             short* dst, int tid){
  for (int i = tid; i < 2048; i += 256){
    int r = i >> 5, s4 = i & 31;
    float4 u = ((const float4*)(base + (size_t)r*(KV*DIM)))[s4];
    uint2 pk; pk.x = pkbf(u.x,u.y); pk.y = pkbf(u.z,u.w);
    *(uint2*)&dst[r*QP + s4*4] = pk;
  }
}
// 64 keys x 128 f32 -> TRANSPOSED bf16 LDS: dst[dim*VP + key]
__device__ __forceinline__ void stage_vt_bf16(const float* __restrict__ base,
                                              short* dst, int tid){
  for (int i = tid; i < 2048; i += 256){
    int key = i & 63, f4 = i >> 6;
    float4 u = ((const float4*)(base + (size_t)key*(KV*DIM)))[f4];
    unsigned p01 = pkbf(u.x,u.y), p23 = pkbf(u.z,u.w);
    dst[(f4*4+0)*VP + key] = (short)(p01 & 0xffffu);
    dst[(f4*4+1)*VP + key] = (short)(p01 >> 16);
    dst[(f4*4+2)*VP + key] = (short)(p23 & 0xffffu);
    dst[(f4*4+3)*VP + key] = (short)(p23 >> 16);
  }
}

// ---------------- kernel 1: block compression (fp32 out to ws) --------------
__global__ __launch_bounds__(256) void compress_k(
    const float* __restrict__ k, const float* __restrict__ v,
    const float* __restrict__ w_k, const float* __restrict__ b_k,
    const float* __restrict__ w_v, const float* __restrict__ b_v,
    float* __restrict__ Kc, float* __restrict__ Vc)
{
  __shared__ float wk[64], wv[64];
  if (threadIdx.x < 64){
    wk[threadIdx.x] = w_k[threadIdx.x];
    wv[threadIdx.x] = w_v[threadIdx.x];
  }
  __syncthreads();
  int t = blockIdx.x * 256 + threadIdx.x;
  if (t >= NB*KV*NBLK*DIM) return;
  int e  = t & (DIM-1);
  int n  = (t >> 7)  & (NBLK-1);
  int g  = (t >> 12) & (KV-1);
  int bb = t >> 13;
  float ak = 0.f, av = 0.f;
  size_t base = ((size_t)(bb*SEQ + n*64) * KV + g) * DIM + e;
  for (int tt = 0; tt < 64; ++tt){
    ak += k[base + (size_t)tt * KV * DIM] * wk[tt];
    av += v[base + (size_t)tt * KV * DIM] * wv[tt];
  }
  Kc[t] = ak + b_k[0];
  Vc[t] = av + b_v[0];
}

// ------- kernel 2: compressed attention (fp32 VALU; exact pooled P) ---------
__global__ __launch_bounds__(256) void cmp_attn_k(
    const float* __restrict__ q, const float* __restrict__ Kc,
    const float* __restrict__ Vc,
    const float* __restrict__ w_gate, const float* __restrict__ b_gate,
    float* __restrict__ pooled_part, float* __restrict__ out)
{
  int blk = blockIdx.x;
  int h  = blk & 3;
  int qb = (blk >> 2) & (NQB-1);
  int g  = (blk >> 7) & 1;
  int bb = blk >> 8;
  int tid = threadIdx.x;
  int qi = tid >> 2, c = tid & 3;

  __shared__ float Ks[32*RS];
  __shared__ float Vs[32*RS];
  __shared__ float wsum[4][NBLK];

  const float4* Ksrc = (const float4*)(Kc + (size_t)(bb*KV + g) * NBLK * DIM);
  const float4* Vsrc = (const float4*)(Vc + (size_t)(bb*KV + g) * NBLK * DIM);
  for (int i = tid; i < 1024; i += 256){
    int row = i >> 5, seg = i & 31;
    int dst = row*RS + (seg>>3)*QS + (seg&7)*4;
    ((float4*)(Ks+dst))[0] = Ksrc[i];
    ((float4*)(Vs+dst))[0] = Vsrc[i];
  }
  __syncthreads();

  int row = bb*SEQ + qb*64 + qi;
  float qv[32];
  {
    const float4* q4 = (const float4*)(q + ((size_t)row*QH + g*NH + h)*DIM + c*32);
#pragma unroll
    for (int j = 0; j < 8; ++j){
      float4 u = q4[j];
      qv[4*j+0]=u.x; qv[4*j+1]=u.y; qv[4*j+2]=u.z; qv[4*j+3]=u.w;
    }
  }

  float gp = 0.f;
#pragma unroll
  for (int d = 0; d < 32; ++d) gp += qv[d]*w_gate[(c*32+d)*3 + 0];
  gp += __shfl_xor(gp, 1); gp += __shfl_xor(gp, 2);
  float g0 = 1.f/(1.f + expf(-(gp + b_gate[0])));

  float sc[NBLK];
#pragma unroll
  for (int n = 0; n < NBLK; ++n){
    float p = 0.f;
    const float4* kr = (const float4*)(Ks + n*RS + c*QS);
#pragma unroll
    for (int j = 0; j < 8; ++j){
      float4 u = kr[j];
      p += qv[4*j+0]*u.x + qv[4*j+1]*u.y + qv[4*j+2]*u.z + qv[4*j+3]*u.w;
    }
    p += __shfl_xor(p, 1); p += __shfl_xor(p, 2);
    sc[n] = p * SCALE;
  }
  float m = sc[0];
#pragma unroll
  for (int n = 1; n < NBLK; ++n) m = fmaxf(m, sc[n]);
  float l = 0.f;
#pragma unroll
  for (int n = 0; n < NBLK; ++n){ sc[n] = expf(sc[n]-m); l += sc[n]; }
  float inv = 1.f/l;
#pragma unroll
  for (int n = 0; n < NBLK; ++n) sc[n] *= inv;

#pragma unroll
  for (int n = 0; n < NBLK; ++n){
    float t2 = sc[n];
    t2 += __shfl_xor(t2, 4); t2 += __shfl_xor(t2, 8);
    t2 += __shfl_xor(t2, 16); t2 += __shfl_xor(t2, 32);
    if ((tid & 63) == 0) wsum[tid>>6][n] = t2;
  }
  __syncthreads();
  if (tid < NBLK)
    pooled_part[(size_t)blk*NBLK + tid] =
        (wsum[0][tid]+wsum[1][tid]) + (wsum[2][tid]+wsum[3][tid]);

  float o[32];
#pragma unroll
  for (int d = 0; d < 32; ++d) o[d] = 0.f;
#pragma unroll
  for (int n = 0; n < NBLK; ++n){
    float pb = sc[n];
    const float4* vr = (const float4*)(Vs + n*RS + c*QS);
#pragma unroll
    for (int j = 0; j < 8; ++j){
      float4 u = vr[j];
      o[4*j+0] += pb*u.x; o[4*j+1] += pb*u.y;
      o[4*j+2] += pb*u.z; o[4*j+3] += pb*u.w;
    }
  }
  float* op = out + ((size_t)row*QH + g*NH + h)*DIM + c*32;
#pragma unroll
  for (int d = 0; d < 32; ++d) op[d] = g0*o[d];   // overwrite (first branch)
}

// ---- kernel 3: fused topk + selected + window attention (MFMA) -------------
// block=(bb,g,qb,h); 4 waves x 16-q strips. Verified layouts (m89/m91/m120):
// A[m=lane&15][k=quad*8+j], B[k=quad*8+j][n=lane&15], C[col=lane&15,row=quad*4+r]
__global__ __launch_bounds__(256, 3) void attn_k(
    const float* __restrict__ q, const float* __restrict__ k,
    const float* __restrict__ v, const float* __restrict__ pp,
    const float* __restrict__ w_gate, const float* __restrict__ b_gate,
    float* __restrict__ out)
{
  int blk = blockIdx.x;
  int h  = blk & 3;
  int qb = (blk >> 2) & (NQB-1);
  int g  = (blk >> 7) & 1;
  int bb = blk >> 8;
  int tid = threadIdx.x;
  int lane = tid & 63, w = tid >> 6, quad = lane >> 4, l15 = lane & 15;

  __shared__ short Ks[64*QP];     // 17.0 KB
  __shared__ short VTs[128*VP];   // 18.0 KB
  __shared__ short Ps[64*VP];     //  9.0 KB
  __shared__ float gbuf[2][64];
  __shared__ int   idxs[NTOP];

  // ---- top-k (wave 0; lanes 0..31 hold pooled sums; lax.top_k tie rule) ----
  if (tid < 64){
    int n = lane;
    float val = -INFINITY;
    if (n < NBLK){
      const float* p0 = pp + ((size_t)((bb*KV+g)*NQB + qb)*NH)*NBLK + n;
      val = (p0[0] + p0[NBLK]) + (p0[2*NBLK] + p0[3*NBLK]);
    }
    for (int t = 0; t < NTOP; ++t){
      float bv = val; int bi = n;
      for (int mm = 1; mm < 32; mm <<= 1){
        float ov = __shfl_xor(bv, mm);
        int   oi = __shfl_xor(bi, mm);
        if (ov > bv || (ov == bv && oi < bi)){ bv = ov; bi = oi; }
      }
      if (lane == 0) idxs[t] = bi;
      if (n == bi) val = -INFINITY;
    }
  }

  // ---- Q fragments direct from global + exact fp32 gate logits ----
  const float* qrow = q + ((size_t)(bb*SEQ + qb*64 + w*16 + l15)*QH + g*NH + h)*DIM;
  bf16x8 qfrag[4];
  float gp1 = 0.f, gp2 = 0.f;
#pragma unroll
  for (int kc = 0; kc < 4; ++kc){
    int d0 = kc*32 + quad*8;
    float4 u0 = *(const float4*)(qrow + d0);
    float4 u1 = *(const float4*)(qrow + d0 + 4);
    float qf[8] = {u0.x,u0.y,u0.z,u0.w,u1.x,u1.y,u1.z,u1.w};
#pragma unroll
    for (int j = 0; j < 8; ++j){
      gp1 += qf[j]*w_gate[(d0+j)*3 + 1];
      gp2 += qf[j]*w_gate[(d0+j)*3 + 2];
    }
    union { unsigned u[4]; bf16x8 v8; } tq;
    tq.u[0] = pkbf(u0.x,u0.y); tq.u[1] = pkbf(u0.z,u0.w);
    tq.u[2] = pkbf(u1.x,u1.y); tq.u[3] = pkbf(u1.z,u1.w);
    qfrag[kc] = tq.v8;
  }
  gp1 += __shfl_xor(gp1,16); gp1 += __shfl_xor(gp1,32);
  gp2 += __shfl_xor(gp2,16); gp2 += __shfl_xor(gp2,32);
  if (quad == 0){
    gbuf[0][w*16+l15] = 1.f/(1.f + __expf(-(gp1 + b_gate[1])));
    gbuf[1][w*16+l15] = 1.f/(1.f + __expf(-(gp2 + b_gate[2])));
  }
  __syncthreads();   // gbuf + idxs visible
  float g1v[4], g2v[4];
#pragma unroll
  for (int r = 0; r < 4; ++r){
    g1v[r] = gbuf[0][w*16+quad*4+r];
    g2v[r] = gbuf[1][w*16+quad*4+r];
  }

  const float* kbase = k + ((size_t)(bb*SEQ)*KV + g)*DIM;
  const float* vbase = v + ((size_t)(bb*SEQ)*KV + g)*DIM;

  float m1[4], l1[4];
  f32x4 oacc[8], wacc[8];
  const f32x4 zero4 = {0.f,0.f,0.f,0.f};
#pragma unroll
  for (int r = 0; r < 4; ++r){ m1[r] = -INFINITY; l1[r] = 0.f; }
#pragma unroll
  for (int dt = 0; dt < 8; ++dt){ oacc[dt] = zero4; wacc[dt] = zero4; }

  // ================= selected-block phase ===================================
  for (int t = 0; t < NTOP; ++t){
    __syncthreads();
    int n = idxs[t];
    stage_k_bf16 (kbase + (size_t)n*64*KV*DIM, Ks, tid);
    stage_vt_bf16(vbase + (size_t)n*64*KV*DIM, VTs, tid);
    __syncthreads();

    f32x4 sacc[4];
#pragma unroll
    for (int nt = 0; nt < 4; ++nt) sacc[nt] = zero4;
#pragma unroll
    for (int kc = 0; kc < 4; ++kc){
      bf16x8 a = qfrag[kc];
#pragma unroll
      for (int nt = 0; nt < 4; ++nt){
        bf16x8 b = *(bf16x8*)&Ks[(nt*16 + l15)*QP + kc*32 + quad*8];
        sacc[nt] = __builtin_amdgcn_mfma_f32_16x16x32_bf16(a, b, sacc[nt], 0, 0, 0);
      }
    }
    float alpha[4];
#pragma unroll
    for (int r = 0; r < 4; ++r){
      float mx = -INFINITY;
#pragma unroll
      for (int nt = 0; nt < 4; ++nt){
        float sv = sacc[nt][r]*SCALE;
        sacc[nt][r] = sv;
        mx = fmaxf(mx, sv);
      }
      mx = fmaxf(mx, __shfl_xor(mx,1)); mx = fmaxf(mx, __shfl_xor(mx,2));
      mx = fmaxf(mx, __shfl_xor(mx,4)); mx = fmaxf(mx, __shfl_xor(mx,8));
      float mn = fmaxf(m1[r], mx);
      alpha[r] = __expf(m1[r] - mn);
      float s0 = 0.f;
#pragma unroll
      for (int nt = 0; nt < 4; ++nt){
        float pe = __expf(sacc[nt][r] - mn);
        sacc[nt][r] = pe;
        s0 += pe;
      }
      s0 += __shfl_xor(s0,1); s0 += __shfl_xor(s0,2);
      s0 += __shfl_xor(s0,4); s0 += __shfl_xor(s0,8);
      l1[r] = l1[r]*alpha[r] + s0;
      m1[r] = mn;
    }
#pragma unroll
    for (int nt = 0; nt < 4; ++nt)
#pragma unroll
      for (int r = 0; r < 4; ++r)
        Ps[(w*16 + quad*4 + r)*VP + nt*16 + l15] = (short)f2b(sacc[nt][r]);
#pragma unroll
    for (int dt = 0; dt < 8; ++dt)
#pragma unroll
      for (int r = 0; r < 4; ++r) oacc[dt][r] *= alpha[r];
#pragma unroll
    for (int kc2 = 0; kc2 < 2; ++kc2){
      bf16x8 pa = *(bf16x8*)&Ps[(w*16 + l15)*VP + kc2*32 + quad*8];
#pragma unroll
      for (int dt = 0; dt < 8; ++dt){
        bf16x8 vb8 = *(bf16x8*)&VTs[(dt*16 + l15)*VP + kc2*32 + quad*8];
        oacc[dt] = __builtin_amdgcn_mfma_f32_16x16x32_bf16(pa, vb8, oacc[dt], 0, 0, 0);
      }
    }
  }
  // finalize slc into oacc; free m1/l1 for the window phase
#pragma unroll
  for (int r = 0; r < 4; ++r){
    float s1 = g1v[r]/l1[r];
#pragma unroll
    for (int dt = 0; dt < 8; ++dt) oacc[dt][r] *= s1;
    m1[r] = -INFINITY; l1[r] = 0.f;
  }

  // ================= sliding-window phase ===================================
  int kb0 = (qb >= 8) ? (qb - 8) : 0;
  for (int kb = kb0; kb <= qb; ++kb){
    bool mlow  = (kb == qb - 8);   // valid: key >= qi
    bool mhigh = (kb == qb);       // valid: key <= qi
    __syncthreads();
    stage_k_bf16 (kbase + (size_t)kb*64*KV*DIM, Ks, tid);
    stage_vt_bf16(vbase + (size_t)kb*64*KV*DIM, VTs, tid);
    __syncthreads();

    f32x4 sacc[4];
#pragma unroll
    for (int nt = 0; nt < 4; ++nt) sacc[nt] = zero4;
#pragma unroll
    for (int kc = 0; kc < 4; ++kc){
      bf16x8 a = qfrag[kc];
#pragma unroll
      for (int nt = 0; nt < 4; ++nt){
        bf16x8 b = *(bf16x8*)&Ks[(nt*16 + l15)*QP + kc*32 + quad*8];
        sacc[nt] = __builtin_amdgcn_mfma_f32_16x16x32_bf16(a, b, sacc[nt], 0, 0, 0);
      }
    }
    float alpha[4];
#pragma unroll
    for (int r = 0; r < 4; ++r){
      int qi_local = w*16 + quad*4 + r;
      float mx = -INFINITY;
#pragma unroll
      for (int nt = 0; nt < 4; ++nt){
        int key = nt*16 + l15;
        float sv = sacc[nt][r]*SCALE;
        bool valid = (!mlow || key >= qi_local) && (!mhigh || key <= qi_local);
        sv = valid ? sv : -INFINITY;
        sacc[nt][r] = sv;
        mx = fmaxf(mx, sv);
      }
      mx = fmaxf(mx, __shfl_xor(mx,1)); mx = fmaxf(mx, __shfl_xor(mx,2));
      mx = fmaxf(mx, __shfl_xor(mx,4)); mx = fmaxf(mx, __shfl_xor(mx,8));
      float mn = fmaxf(m1[r], mx);
      alpha[r] = __expf(m1[r] - mn);
      float s0 = 0.f;
#pragma unroll
      for (int nt = 0; nt < 4; ++nt){
        float pe = __expf(sacc[nt][r] - mn);   // masked -> 0
        sacc[nt][r] = pe;
        s0 += pe;
      }
      s0 += __shfl_xor(s0,1); s0 += __shfl_xor(s0,2);
      s0 += __shfl_xor(s0,4); s0 += __shfl_xor(s0,8);
      l1[r] = l1[r]*alpha[r] + s0;
      m1[r] = mn;
    }
#pragma unroll
    for (int nt = 0; nt < 4; ++nt)
#pragma unroll
      for (int r = 0; r < 4; ++r)
        Ps[(w*16 + quad*4 + r)*VP + nt*16 + l15] = (short)f2b(sacc[nt][r]);
#pragma unroll
    for (int dt = 0; dt < 8; ++dt)
#pragma unroll
      for (int r = 0; r < 4; ++r) wacc[dt][r] *= alpha[r];
#pragma unroll
    for (int kc2 = 0; kc2 < 2; ++kc2){
      bf16x8 pa = *(bf16x8*)&Ps[(w*16 + l15)*VP + kc2*32 + quad*8];
#pragma unroll
      for (int dt = 0; dt < 8; ++dt){
        bf16x8 vb8 = *(bf16x8*)&VTs[(dt*16 + l15)*VP + kc2*32 + quad*8];
        wacc[dt] = __builtin_amdgcn_mfma_f32_16x16x32_bf16(pa, vb8, wacc[dt], 0, 0, 0);
      }
    }
  }

  // ---- epilogue: out += slc + win (single RMW) ----
#pragma unroll
  for (int r = 0; r < 4; ++r){
    float s2 = g2v[r]/l1[r];
    float* op = out + ((size_t)(bb*SEQ + qb*64 + w*16 + quad*4 + r)*QH + g*NH + h)*DIM + l15;
#pragma unroll
    for (int dt = 0; dt < 8; ++dt)
      op[dt*16] += oacc[dt][r] + s2*wacc[dt][r];
  }
}

extern "C" void kernel_launch(void* const* d_in, const int* in_sizes, int n_in,
                              void* d_out, int out_size, void* d_ws, size_t ws_size,
                              hipStream_t stream) {
  const float* q      = (const float*)d_in[0];
  const float* k      = (const float*)d_in[1];
  const float* v      = (const float*)d_in[2];
  const float* w_k    = (const float*)d_in[3];
  const float* b_k    = (const float*)d_in[4];
  const float* w_v    = (const float*)d_in[5];
  const float* b_v    = (const float*)d_in[6];
  const float* w_gate = (const float*)d_in[7];
  const float* b_gate = (const float*)d_in[8];
  float* out = (float*)d_out;

  float* ws = (float*)d_ws;
  float* Kc = ws;                     // 16384 f32
  float* Vc = ws + 16384;             // 16384 f32
  float* pp = ws + 32768;             // 512*32 f32 (per-head pooled partials)

  compress_k<<<64, 256, 0, stream>>>(k, v, w_k, b_k, w_v, b_v, Kc, Vc);
  cmp_attn_k<<<NB*KV*NQB*NH, 256, 0, stream>>>(q, Kc, Vc, w_gate, b_gate, pp, out);
  attn_k    <<<NB*KV*NQB*NH, 256, 0, stream>>>(q, k, v, pp, w_gate, b_gate, out);
}